// Round 19
// baseline (233.278 us; speedup 1.0000x reference)
//
#include <hip/hip_runtime.h>
#include <cstdint>

typedef __attribute__((ext_vector_type(8))) short short8;
typedef __attribute__((ext_vector_type(8))) __bf16 bf16x8;
typedef __attribute__((ext_vector_type(4))) float f32x4;

__device__ __forceinline__ uint32_t cvt_pk_bf16(float lo, float hi) {
  uint32_t r;
  asm("v_cvt_pk_bf16_f32 %0, %1, %2" : "=v"(r) : "v"(lo), "v"(hi));
  return r;
}

__device__ __forceinline__ short f2bf(float f) {  // 1-op RNE via cvt_pk
  return (short)cvt_pk_bf16(f, f);
}

__device__ __forceinline__ float exp2_fast(float x) {
  return __builtin_amdgcn_exp2f(x);  // v_exp_f32 (native 2^x)
}

// compiler-level memory fence (no instruction emitted)
__device__ __forceinline__ void mem_fence_compiler() {
  asm volatile("" ::: "memory");
}

__device__ __forceinline__ void gload_lds16(const void* g, void* l) {
  __builtin_amdgcn_global_load_lds(
      (const __attribute__((address_space(1))) void*)(uintptr_t)g,
      (__attribute__((address_space(3))) void*)(uint32_t)(uintptr_t)l,
      16, 0, 0);
}

// ---------------- conversion kernels ----------------

__global__ __launch_bounds__(256) void cvt_f32_bf16(const float* __restrict__ s,
                                                    short* __restrict__ d, long n) {
  long i = ((long)blockIdx.x * 256 + threadIdx.x) * 8;
  if (i + 8 > n) return;
  const float4 a = *(const float4*)(s + i);
  const float4 b = *(const float4*)(s + i + 4);
  uint4 o;
  o.x = cvt_pk_bf16(a.x, a.y);
  o.y = cvt_pk_bf16(a.z, a.w);
  o.z = cvt_pk_bf16(b.x, b.y);
  o.w = cvt_pk_bf16(b.z, b.w);
  *(uint4*)(d + i) = o;
}

// three NW-sized tensors in one launch (Wk, Wv, Wo)
__global__ __launch_bounds__(256) void cvt3_f32_bf16(
    const float* __restrict__ s0, short* __restrict__ d0,
    const float* __restrict__ s1, short* __restrict__ d1,
    const float* __restrict__ s2, short* __restrict__ d2) {
  const int which = blockIdx.x >> 9;             // 512 blocks per tensor
  const long i = (((long)(blockIdx.x & 511)) * 256 + threadIdx.x) * 8;
  const float* s = which == 0 ? s0 : (which == 1 ? s1 : s2);
  short* d = which == 0 ? d0 : (which == 1 ? d1 : d2);
  const float4 a = *(const float4*)(s + i);
  const float4 b = *(const float4*)(s + i + 4);
  uint4 o;
  o.x = cvt_pk_bf16(a.x, a.y);
  o.y = cvt_pk_bf16(a.z, a.w);
  o.z = cvt_pk_bf16(b.x, b.y);
  o.w = cvt_pk_bf16(b.z, b.w);
  *(uint4*)(d + i) = o;
}

// transpose-convert: z==0 -> Wq^T into wqt; z>=1 -> M[z-1]^T into Mt[z-1]
__global__ __launch_bounds__(256) void cvtT5(const float* __restrict__ Wq,
                                             short* __restrict__ wqt,
                                             const float* __restrict__ M,
                                             short* __restrict__ Mt) {
  __shared__ short t[64][65];
  const int tid = threadIdx.x;
  const int z = blockIdx.z;
  const float* src = z == 0 ? Wq : M + (long)(z - 1) * 1024 * 1024;
  short* dst = z == 0 ? wqt : Mt + (long)(z - 1) * 1024 * 1024;
  const int d0 = blockIdx.x * 64, e0 = blockIdx.y * 64;
#pragma unroll
  for (int k = 0; k < 16; ++k) {
    int idx = k * 256 + tid; int r = idx >> 6, c = idx & 63;
    t[r][c] = f2bf(src[(long)(d0 + r) * 1024 + e0 + c]);
  }
  __syncthreads();
#pragma unroll
  for (int k = 0; k < 16; ++k) {
    int idx = k * 256 + tid; int r = idx >> 6, c = idx & 63;
    dst[(long)(e0 + r) * 1024 + d0 + c] = t[c][r];
  }
}

// mask tile flags: flags[qt*32+tt] = any nonzero in 64x64 tile
__global__ __launch_bounds__(256) void mask_flags(const float* __restrict__ mask,
                                                  int* __restrict__ flags) {
  __shared__ int f;
  const int tid = threadIdx.x;
  if (tid == 0) f = 0;
  __syncthreads();
  const int qt = blockIdx.x, tt = blockIdx.y;
  const float* base = mask + (long)qt * 64 * 2048 + tt * 64;
  const int r = tid >> 2, c = (tid & 3) * 16;
  bool nz = false;
#pragma unroll
  for (int k = 0; k < 4; ++k) {
    float4 v = *(const float4*)(base + (long)r * 2048 + c + k * 4);
    nz = nz | (v.x != 0.f) | (v.y != 0.f) | (v.z != 0.f) | (v.w != 0.f);
  }
  if (nz) f = 1;
  __syncthreads();
  if (tid == 0) flags[qt * 32 + tt] = f;
}

// ---------------- GEMM core: 128x128 tile = scale * A * B^T (bf16 in, f32 acc) ----------
// BK=32, TRIPLE-buffered (prefetch depth 2, steady vmcnt(8)). Verified
// 2-barrier skeleton (rounds 8-18). If vt != nullptr the epilogue stores
// TRANSPOSED into vt[(bx>>4)*16+by*2+..][dh][s] via an LDS round-trip
// (stride 136 shorts, 2-way-conflict-free) instead of writing C.

template <typename CT>
__device__ __forceinline__ void gemm_core(
    short* pool, const short* __restrict__ Ab, const short* __restrict__ Bb,
    CT* __restrict__ Cb, int N, int K, float scale, short* __restrict__ vt,
    int bx, int by) {
  short* Asb = pool;
  short* Bsb = pool + 12288;
  const int tid = threadIdx.x;
  const int w = tid >> 6, lane = tid & 63;
  const int wr = w >> 1, wc = w & 1;
  const int g = lane >> 4;

  f32x4 acc[4][4];
#pragma unroll
  for (int i = 0; i < 4; ++i)
#pragma unroll
    for (int j = 0; j < 4; ++j) acc[i][j] = {0.f, 0.f, 0.f, 0.f};

  const int srow = lane >> 2;                      // row within 16-row chunk
  const int scol = ((lane & 3) ^ (srow & 3)) * 8;  // pre-swizzled source col (shorts)

  auto STAGE = [&](int bufi, int k0) {
#pragma unroll
    for (int c = 0; c < 2; ++c) {
      const int chunk = w * 2 + c;
      const long gr = (long)(chunk * 16 + srow);
      gload_lds16(Ab + gr * K + k0 + scol, Asb + bufi * 4096 + chunk * 512);
      gload_lds16(Bb + gr * K + k0 + scol, Bsb + bufi * 4096 + chunk * 512);
    }
  };

  auto COMPUTE = [&](int bufi) {
    bf16x8 af[4], bfr[4];
#pragma unroll
    for (int mf = 0; mf < 4; ++mf) {
      const int r = wr * 64 + mf * 16 + (lane & 15);
      const int cb = g ^ (r & 3);
      af[mf] = *(const bf16x8*)&Asb[bufi * 4096 + r * 32 + cb * 8];
    }
#pragma unroll
    for (int nf = 0; nf < 4; ++nf) {
      const int r = wc * 64 + nf * 16 + (lane & 15);
      const int cb = g ^ (r & 3);
      bfr[nf] = *(const bf16x8*)&Bsb[bufi * 4096 + r * 32 + cb * 8];
    }
#pragma unroll
    for (int mf = 0; mf < 4; ++mf)
#pragma unroll
      for (int nf = 0; nf < 4; ++nf)
        acc[mf][nf] =
            __builtin_amdgcn_mfma_f32_16x16x32_bf16(af[mf], bfr[nf], acc[mf][nf], 0, 0, 0);
  };

  const int NK = K >> 5;
  STAGE(0, 0);
  if (NK > 1) STAGE(1, 32);
  for (int it = 0; it < NK; ++it) {
    const int cur = it % 3;
    if (it + 2 < NK) {
      STAGE((it + 2) % 3, (it + 2) * 32);
      asm volatile("s_waitcnt vmcnt(8)" ::: "memory");  // cur-buffer loads done
    } else if (it + 1 < NK) {
      asm volatile("s_waitcnt vmcnt(4)" ::: "memory");
    } else {
      asm volatile("s_waitcnt vmcnt(0)" ::: "memory");
    }
    __builtin_amdgcn_s_barrier();
    __builtin_amdgcn_sched_barrier(0);
    COMPUTE(cur);
    __builtin_amdgcn_sched_barrier(0);
    __builtin_amdgcn_s_barrier();
  }

  const int r0 = g * 4, cc = lane & 15;
  if (vt != nullptr) {
    // ---- fused V^T epilogue: acc -> LDS[dh][s] (stride 136) -> coalesced Vt
    __syncthreads();  // all waves done with As/Bs region
#pragma unroll
    for (int mf = 0; mf < 4; ++mf)
#pragma unroll
      for (int i = 0; i < 4; ++i) {
        const int srow_l = wr * 64 + mf * 16 + r0 + i;  // s within tile
#pragma unroll
        for (int nf = 0; nf < 4; ++nf) {
          const int dh_l = wc * 64 + nf * 16 + cc;      // dh within tile
          pool[dh_l * 136 + srow_l] = f2bf(acc[mf][nf][i]);
        }
      }
    __syncthreads();
    const long bb = bx >> 4;             // batch
    const int s0b = (bx & 15) * 128;     // s within batch
    const int hbase = by * 2;
#pragma unroll
    for (int pass = 0; pass < 4; ++pass) {
      const int dhrow = pass * 32 + (tid >> 3);  // 0..127
      const long vrow = (bb * 16 + hbase + (dhrow >> 6)) * 64 + (dhrow & 63);
      const int cseg = (tid & 7) * 16;
      bf16x8 v0 = *(const bf16x8*)&pool[dhrow * 136 + cseg];
      bf16x8 v1 = *(const bf16x8*)&pool[dhrow * 136 + cseg + 8];
      *(bf16x8*)(vt + vrow * 2048 + s0b + cseg) = v0;
      *(bf16x8*)(vt + vrow * 2048 + s0b + cseg + 8) = v1;
    }
    return;
  }

#pragma unroll
  for (int mf = 0; mf < 4; ++mf)
#pragma unroll
    for (int i = 0; i < 4; ++i) {
      const long row = (long)bx * 128 + wr * 64 + mf * 16 + r0 + i;
#pragma unroll
      for (int nf = 0; nf < 4; ++nf) {
        const long col = (long)by * 128 + wc * 64 + nf * 16 + cc;
        float v = acc[mf][nf][i] * scale;
        if constexpr (__is_same(CT, short))
          Cb[row * (long)N + col] = f2bf(v);
        else
          Cb[row * (long)N + col] = v;
      }
    }
}

// generic batched wrapper (QM, out-proj)
template <typename CT>
__global__ __launch_bounds__(256) void gemm_bt(
    const short* __restrict__ A, const short* __restrict__ B, CT* __restrict__ C,
    int N, int K, long sA, long sB, long sC, float scale) {
  __shared__ __align__(16) short pool[24576];  // 48KB
  const int bx = blockIdx.x, by = blockIdx.y, bz = blockIdx.z;
  gemm_core<CT>(pool, A + (long)bz * sA + (long)bx * 128 * K,
                B + (long)bz * sB + (long)by * 128 * K, C + (long)bz * sC,
                N, K, scale, nullptr, bx, by);
}

// fused KV-projection + Gt, ZERO dead blocks: 1D grid of 1280 blocks.
// p in [0,1024): KV  (z = p>>9, y = (p&511)>>6, x = p&63; z==1 -> Vt epilogue)
// p in [1024,1280): Gt (zz = (p-1024)>>6, y = ((p-1024)&63)>>3, x = (p-1024)&7)
__global__ __launch_bounds__(256) void kvgt_gemm(
    const short* __restrict__ xb, const short* __restrict__ wkv,
    short* __restrict__ Kb, short* __restrict__ Vtb,
    const short* __restrict__ Mtb, const short* __restrict__ wqt,
    short* __restrict__ Gtb) {
  __shared__ __align__(16) short pool[24576];  // 48KB
  constexpr long NW = 1024l * 1024, NX = 4l * 2048 * 1024;
  const int p = blockIdx.x;
  if (p < 1024) {
    const int z = p >> 9, rem = p & 511;
    const int by = rem >> 6, bx = rem & 63;  // original (64,8) order, x fastest
    gemm_core<short>(pool, xb + (long)bx * 128 * 1024,
                     wkv + (long)z * NW + (long)by * 128 * 1024,
                     Kb + (long)z * NX, 1024, 1024, 1.0f,
                     z == 1 ? Vtb : nullptr, bx, by);
  } else {
    const int r = p - 1024;
    const int zz = r >> 6, rr = r & 63;
    const int by = rr >> 3, bx = rr & 7;     // original (8,8) order, x fastest
    gemm_core<short>(pool, Mtb + (long)zz * NW + (long)bx * 128 * 1024,
                     wqt + (long)by * 128 * 1024, Gtb + (long)zz * NW,
                     1024, 1024, 1.0f, nullptr, bx, by);
  }
}

// ---------------- flash attention ----------------
// Round-17/18 skeleton (8 waves, 32 q-rows/wave as two sequential 16-q passes)
// with SHARED K-fragment reads: both passes' QK^T MFMAs are computed upfront,
// each kf LDS read feeding two MFMAs (sacc0 from qf0, sacc1 from qf1) - a pure
// register-level change (sacc1 stays live across pass A; no LDS layout,
// lifetime, or barrier changes vs the verified kernel). Softmax+P+PV run
// strictly sequentially per pass, byte-identical to round 17.
// LDS reads per tile per wave: 36 -> 28 (-22%).

__global__ __launch_bounds__(512) void flash_attn(
    const short* __restrict__ QM, const short* __restrict__ Kb,
    const short* __restrict__ Vt, const float* __restrict__ mask,
    const int* __restrict__ mflags, short* __restrict__ AO) {
  constexpr int S = 2048, D = 1024, NT = S / 64;
  constexpr float LOG2E = 1.44269504088896f;
  constexpr float CLIP = 50.0f * LOG2E;
  __shared__ __align__(16) short Ks[2][64 * 64];
  __shared__ __align__(16) short Vs[2][64 * 64];
  __shared__ __align__(16) short Ps[8][16 * 64];
  const int tid = threadIdx.x;
  const int w = tid >> 6, lane = tid & 63;
  const int q = lane & 15, g = lane >> 4;
  const int q0 = blockIdx.x * 256;
  const int h = blockIdx.y;
  const long b = blockIdx.z;

  const short* QMb = QM + (b * S) * D + h * 64;
  const short* Kbp = Kb + (b * S) * D + h * 64;
  const short* Vtp = Vt + ((b * 16 + h) * 64) * S;
  const int qw = q0 + w * 32;  // this wave's 32 q-rows

  bf16x8 qf0[2], qf1[2];
#pragma unroll
  for (int ks = 0; ks < 2; ++ks) {
    qf0[ks] = *(const bf16x8*)(QMb + (long)(qw + q) * D + ks * 32 + g * 8);
    qf1[ks] = *(const bf16x8*)(QMb + (long)(qw + 16 + q) * D + ks * 32 + g * 8);
  }

  bf16x8 onesf;
#pragma unroll
  for (int j = 0; j < 8; ++j) onesf[j] = (__bf16)1.0f;

  f32x4 accA[4], accB[4];
#pragma unroll
  for (int f = 0; f < 4; ++f) {
    accA[f] = {0.f, 0.f, 0.f, 0.f};
    accB[f] = {0.f, 0.f, 0.f, 0.f};
  }
  f32x4 acc_lA = {0.f, 0.f, 0.f, 0.f};
  f32x4 acc_lB = {0.f, 0.f, 0.f, 0.f};

  const int srow8 = lane >> 3;
  const int scol8 = ((lane & 7) ^ (srow8 & 7)) * 8;
  short* Pw = &Ps[w][0];
  const int psw = (q & 7) << 3;

  auto STAGE = [&](int bufi, int t0) {
    const int row = w * 8 + srow8;
    gload_lds16(Kbp + (long)(t0 + row) * D + scol8, &Ks[bufi][w * 512]);
    gload_lds16(Vtp + (long)row * S + t0 + scol8, &Vs[bufi][w * 512]);
  };

  // QK^T for BOTH passes with shared kf reads (one read -> two MFMAs)
  auto QK2 = [&](int bufi, f32x4 (&s0)[4], f32x4 (&s1)[4]) {
#pragma unroll
    for (int nf = 0; nf < 4; ++nf) {
      s0[nf] = {0.f, 0.f, 0.f, 0.f};
      s1[nf] = {0.f, 0.f, 0.f, 0.f};
    }
    __builtin_amdgcn_s_setprio(1);
#pragma unroll
    for (int ks = 0; ks < 2; ++ks) {
#pragma unroll
      for (int nf = 0; nf < 4; ++nf) {
        const int r = nf * 16 + q;
        const int blk = (ks * 4 + g) ^ (r & 7);
        bf16x8 kf = *(const bf16x8*)&Ks[bufi][r * 64 + blk * 8];
        s0[nf] = __builtin_amdgcn_mfma_f32_16x16x32_bf16(kf, qf0[ks], s0[nf], 0, 0, 0);
        s1[nf] = __builtin_amdgcn_mfma_f32_16x16x32_bf16(kf, qf1[ks], s1[nf], 0, 0, 0);
      }
    }
    __builtin_amdgcn_s_setprio(0);
  };

  // softmax + P store + PV for one 16-q pass (byte-identical to round 17)
  auto SMPV = [&](int bufi, int t0, int qrow, const f32x4 (&sacc)[4],
                  f32x4 (&acc)[4], f32x4& acc_l) {
    float pv[4][4];
    const int* flagrowU = mflags + (qrow >> 6) * 32;
    if (__builtin_expect(flagrowU[t0 >> 6], 0)) {
      const float* mrow = mask + (long)(qrow + q) * S + t0;
#pragma unroll
      for (int nf = 0; nf < 4; ++nf) {
        float4 mv = *(const float4*)(mrow + nf * 16 + 4 * g);
        const float* mp = &mv.x;
#pragma unroll
        for (int i = 0; i < 4; ++i)
          pv[nf][i] = exp2_fast(
              __builtin_amdgcn_fmed3f(sacc[nf][i], -CLIP, CLIP) + LOG2E * mp[i]);
      }
    } else {
#pragma unroll
      for (int nf = 0; nf < 4; ++nf)
#pragma unroll
        for (int i = 0; i < 4; ++i)
          pv[nf][i] = exp2_fast(__builtin_amdgcn_fmed3f(sacc[nf][i], -CLIP, CLIP));
    }
#pragma unroll
    for (int nf = 0; nf < 4; ++nf) {
      uint2 u;
      u.x = cvt_pk_bf16(pv[nf][0], pv[nf][1]);
      u.y = cvt_pk_bf16(pv[nf][2], pv[nf][3]);
      *(uint2*)&Pw[q * 64 + ((nf * 16 + 4 * g) ^ psw)] = u;
    }

    mem_fence_compiler();  // P stores (uint2) precede P loads (bf16x8)

    __builtin_amdgcn_s_setprio(1);
#pragma unroll
    for (int ts = 0; ts < 2; ++ts) {
      bf16x8 pfr = *(const bf16x8*)&Pw[q * 64 + ((ts * 32 + 8 * g) ^ psw)];
#pragma unroll
      for (int f = 0; f < 4; ++f) {
        const int vr = f * 16 + q;
        const int vblk = (ts * 4 + g) ^ (vr & 7);
        bf16x8 vf = *(const bf16x8*)&Vs[bufi][vr * 64 + vblk * 8];
        acc[f] = __builtin_amdgcn_mfma_f32_16x16x32_bf16(vf, pfr, acc[f], 0, 0, 0);
      }
      acc_l = __builtin_amdgcn_mfma_f32_16x16x32_bf16(onesf, pfr, acc_l, 0, 0, 0);
    }
    __builtin_amdgcn_s_setprio(0);
    mem_fence_compiler();  // P loads precede the next pass's P stores
  };

  STAGE(0, 0);
  for (int it = 0; it < NT; ++it) {
    const int cur = it & 1;
    if (it + 1 < NT) {
      STAGE(cur ^ 1, (it + 1) * 64);
      asm volatile("s_waitcnt vmcnt(2)" ::: "memory");  // cur-buffer loads done
    } else {
      asm volatile("s_waitcnt vmcnt(0)" ::: "memory");
    }
    __builtin_amdgcn_s_barrier();
    __builtin_amdgcn_sched_barrier(0);
    f32x4 sacc0[4], sacc1[4];
    QK2(cur, sacc0, sacc1);
    SMPV(cur, it * 64, qw, sacc0, accA, acc_lA);
    SMPV(cur, it * 64, qw + 16, sacc1, accB, acc_lB);
    __builtin_amdgcn_sched_barrier(0);
    __builtin_amdgcn_s_barrier();
  }

  // epilogue per pass: normalize, transpose O^T -> O via wave-private LDS
  const int qr = lane >> 2, c0 = (lane & 3) * 16;
  short* AOp = AO + (b * S) * D + h * 64;
#pragma unroll
  for (int u = 0; u < 2; ++u) {
    const f32x4* acc = (u == 0) ? accA : accB;
    const float inv = 1.0f / ((u == 0) ? acc_lA[0] : acc_lB[0]);
#pragma unroll
    for (int f = 0; f < 4; ++f) {
      uint2 uu;
      uu.x = cvt_pk_bf16(acc[f][0] * inv, acc[f][1] * inv);
      uu.y = cvt_pk_bf16(acc[f][2] * inv, acc[f][3] * inv);
      *(uint2*)&Pw[q * 64 + ((f * 16 + 4 * g) ^ psw)] = uu;
    }
    mem_fence_compiler();  // O stores (uint2) precede transpose loads (bf16x8)
#pragma unroll
    for (int r2 = 0; r2 < 2; ++r2) {
      const int cc2 = c0 + r2 * 8;
      bf16x8 ov = *(const bf16x8*)&Pw[qr * 64 + (cc2 ^ ((qr & 7) << 3))];
      *(bf16x8*)(AOp + (long)(qw + u * 16 + qr) * D + cc2) = ov;
    }
    mem_fence_compiler();  // transpose loads precede next pass's O stores
  }
}

// ---------------- launch ----------------

extern "C" void kernel_launch(void* const* d_in, const int* in_sizes, int n_in,
                              void* d_out, int out_size, void* d_ws, size_t ws_size,
                              hipStream_t stream) {
  const float* x = (const float*)d_in[0];
  const float* M = (const float*)d_in[1];
  const float* mask = (const float*)d_in[2];
  const float* Wq = (const float*)d_in[3];
  const float* Wk = (const float*)d_in[4];
  const float* Wv = (const float*)d_in[5];
  const float* Wo = (const float*)d_in[6];
  float* out = (float*)d_out;

  constexpr long S = 2048, D = 1024;
  constexpr long NX = 4 * S * D;  // 8388608
  constexpr long NW = D * D;      // 1048576
  constexpr float C1 = 0.125f * 1.44269504088896f;  // 1/sqrt(64) * log2(e)

  short* p = (short*)d_ws;
  short* xb = p;   p += NX;
  short* wkb = p;  p += NW;  // wk, wv contiguous (stride NW) for batched K,V proj
  short* wvb = p;  p += NW;
  short* wob = p;  p += NW;
  short* wqt = p;  p += NW;       // Wq^T  [c][d]
  short* Mtb = p;  p += 4 * NW;   // M^T   [b][e][d]
  short* Gtb = p;  p += 4 * NW;   // G^T = M^T Wq  [b][e][c]
  short* Kb = p;   p += NX;       // K (row-major)
  short* QMb = p;  p += NX;
  short* Vtb = p;  p += NX;       // V^T [b*16+h][dh][s] (written by fused epilogue)
  int* flags = (int*)p;  p += 2048;  // 32x32 tile flags (4KB)
  short* AOb = Mtb;  // Mt+Gt region (8*NW == NX shorts) dead after QM -> reuse for AO

  cvt_f32_bf16<<<NX / 2048, 256, 0, stream>>>(x, xb, NX);
  cvt3_f32_bf16<<<1536, 256, 0, stream>>>(Wk, wkb, Wv, wvb, Wo, wob);
  cvtT5<<<dim3(16, 16, 5), 256, 0, stream>>>(Wq, wqt, M, Mtb);  // Wq^T + M^T
  mask_flags<<<dim3(32, 32), 256, 0, stream>>>(mask, flags);

  // K,V projections (V stores transposed to Vtb) + independent G^T GEMM in
  // ONE 1280-block launch, zero dead blocks
  kvgt_gemm<<<1280, 256, 0, stream>>>(xb, wkb, Kb, Vtb, Mtb, wqt, Gtb);
  // QM[b][s][e] = C1 * sum_c x[b][s][c] * Gt[b][e][c]  (fused Q-proj + bilinear,
  // pre-scaled into the log2-softmax domain for flash)
  gemm_bt<short><<<dim3(16, 8, 4), 256, 0, stream>>>(xb, Gtb, QMb, 1024, 1024,
                                                     S * D, NW, S * D, C1);
  flash_attn<<<dim3(8, 16, 4), 512, 0, stream>>>(QMb, Kb, Vtb, mask, flags, AOb);
  // out = AO @ Wo^T (f32 store)
  gemm_bt<float><<<dim3(64, 8, 1), 256, 0, stream>>>(AOb, wob, out, 1024, 1024,
                                                     0, 0, 0, 1.0f);
}

// Round 20
// 218.295 us; speedup vs baseline: 1.0686x; 1.0686x over previous
//
#include <hip/hip_runtime.h>
#include <cstdint>

typedef __attribute__((ext_vector_type(8))) short short8;
typedef __attribute__((ext_vector_type(8))) __bf16 bf16x8;
typedef __attribute__((ext_vector_type(4))) float f32x4;

__device__ __forceinline__ uint32_t cvt_pk_bf16(float lo, float hi) {
  uint32_t r;
  asm("v_cvt_pk_bf16_f32 %0, %1, %2" : "=v"(r) : "v"(lo), "v"(hi));
  return r;
}

__device__ __forceinline__ short f2bf(float f) {  // 1-op RNE via cvt_pk
  return (short)cvt_pk_bf16(f, f);
}

__device__ __forceinline__ float exp2_fast(float x) {
  return __builtin_amdgcn_exp2f(x);  // v_exp_f32 (native 2^x)
}

// compiler-level memory fence (no instruction emitted)
__device__ __forceinline__ void mem_fence_compiler() {
  asm volatile("" ::: "memory");
}

__device__ __forceinline__ void gload_lds16(const void* g, void* l) {
  __builtin_amdgcn_global_load_lds(
      (const __attribute__((address_space(1))) void*)(uintptr_t)g,
      (__attribute__((address_space(3))) void*)(uint32_t)(uintptr_t)l,
      16, 0, 0);
}

// ---------------- conversion kernels ----------------

__global__ __launch_bounds__(256) void cvt_f32_bf16(const float* __restrict__ s,
                                                    short* __restrict__ d, long n) {
  long i = ((long)blockIdx.x * 256 + threadIdx.x) * 8;
  if (i + 8 > n) return;
  const float4 a = *(const float4*)(s + i);
  const float4 b = *(const float4*)(s + i + 4);
  uint4 o;
  o.x = cvt_pk_bf16(a.x, a.y);
  o.y = cvt_pk_bf16(a.z, a.w);
  o.z = cvt_pk_bf16(b.x, b.y);
  o.w = cvt_pk_bf16(b.z, b.w);
  *(uint4*)(d + i) = o;
}

// three NW-sized tensors in one launch (Wk, Wv, Wo)
__global__ __launch_bounds__(256) void cvt3_f32_bf16(
    const float* __restrict__ s0, short* __restrict__ d0,
    const float* __restrict__ s1, short* __restrict__ d1,
    const float* __restrict__ s2, short* __restrict__ d2) {
  const int which = blockIdx.x >> 9;             // 512 blocks per tensor
  const long i = (((long)(blockIdx.x & 511)) * 256 + threadIdx.x) * 8;
  const float* s = which == 0 ? s0 : (which == 1 ? s1 : s2);
  short* d = which == 0 ? d0 : (which == 1 ? d1 : d2);
  const float4 a = *(const float4*)(s + i);
  const float4 b = *(const float4*)(s + i + 4);
  uint4 o;
  o.x = cvt_pk_bf16(a.x, a.y);
  o.y = cvt_pk_bf16(a.z, a.w);
  o.z = cvt_pk_bf16(b.x, b.y);
  o.w = cvt_pk_bf16(b.z, b.w);
  *(uint4*)(d + i) = o;
}

// transpose-convert: z==0 -> Wq^T into wqt; z>=1 -> M[z-1]^T into Mt[z-1]
__global__ __launch_bounds__(256) void cvtT5(const float* __restrict__ Wq,
                                             short* __restrict__ wqt,
                                             const float* __restrict__ M,
                                             short* __restrict__ Mt) {
  __shared__ short t[64][65];
  const int tid = threadIdx.x;
  const int z = blockIdx.z;
  const float* src = z == 0 ? Wq : M + (long)(z - 1) * 1024 * 1024;
  short* dst = z == 0 ? wqt : Mt + (long)(z - 1) * 1024 * 1024;
  const int d0 = blockIdx.x * 64, e0 = blockIdx.y * 64;
#pragma unroll
  for (int k = 0; k < 16; ++k) {
    int idx = k * 256 + tid; int r = idx >> 6, c = idx & 63;
    t[r][c] = f2bf(src[(long)(d0 + r) * 1024 + e0 + c]);
  }
  __syncthreads();
#pragma unroll
  for (int k = 0; k < 16; ++k) {
    int idx = k * 256 + tid; int r = idx >> 6, c = idx & 63;
    dst[(long)(e0 + r) * 1024 + d0 + c] = t[c][r];
  }
}

// mask tile flags: flags[qt*32+tt] = any nonzero in 64x64 tile
__global__ __launch_bounds__(256) void mask_flags(const float* __restrict__ mask,
                                                  int* __restrict__ flags) {
  __shared__ int f;
  const int tid = threadIdx.x;
  if (tid == 0) f = 0;
  __syncthreads();
  const int qt = blockIdx.x, tt = blockIdx.y;
  const float* base = mask + (long)qt * 64 * 2048 + tt * 64;
  const int r = tid >> 2, c = (tid & 3) * 16;
  bool nz = false;
#pragma unroll
  for (int k = 0; k < 4; ++k) {
    float4 v = *(const float4*)(base + (long)r * 2048 + c + k * 4);
    nz = nz | (v.x != 0.f) | (v.y != 0.f) | (v.z != 0.f) | (v.w != 0.f);
  }
  if (nz) f = 1;
  __syncthreads();
  if (tid == 0) flags[qt * 32 + tt] = f;
}

// ---------------- GEMM core: 128x128 tile = scale * A * B^T (bf16 in, f32 acc) ----------
// BK=32, TRIPLE-buffered (prefetch depth 2, steady vmcnt(8)). Verified
// 2-barrier skeleton (rounds 8-18). If vt != nullptr the epilogue stores
// TRANSPOSED into vt[(bx>>4)*16+by*2+..][dh][s] via an LDS round-trip
// (stride 136 shorts, 2-way-conflict-free) instead of writing C.

template <typename CT>
__device__ __forceinline__ void gemm_core(
    short* pool, const short* __restrict__ Ab, const short* __restrict__ Bb,
    CT* __restrict__ Cb, int N, int K, float scale, short* __restrict__ vt,
    int bx, int by) {
  short* Asb = pool;
  short* Bsb = pool + 12288;
  const int tid = threadIdx.x;
  const int w = tid >> 6, lane = tid & 63;
  const int wr = w >> 1, wc = w & 1;
  const int g = lane >> 4;

  f32x4 acc[4][4];
#pragma unroll
  for (int i = 0; i < 4; ++i)
#pragma unroll
    for (int j = 0; j < 4; ++j) acc[i][j] = {0.f, 0.f, 0.f, 0.f};

  const int srow = lane >> 2;                      // row within 16-row chunk
  const int scol = ((lane & 3) ^ (srow & 3)) * 8;  // pre-swizzled source col (shorts)

  auto STAGE = [&](int bufi, int k0) {
#pragma unroll
    for (int c = 0; c < 2; ++c) {
      const int chunk = w * 2 + c;
      const long gr = (long)(chunk * 16 + srow);
      gload_lds16(Ab + gr * K + k0 + scol, Asb + bufi * 4096 + chunk * 512);
      gload_lds16(Bb + gr * K + k0 + scol, Bsb + bufi * 4096 + chunk * 512);
    }
  };

  auto COMPUTE = [&](int bufi) {
    bf16x8 af[4], bfr[4];
#pragma unroll
    for (int mf = 0; mf < 4; ++mf) {
      const int r = wr * 64 + mf * 16 + (lane & 15);
      const int cb = g ^ (r & 3);
      af[mf] = *(const bf16x8*)&Asb[bufi * 4096 + r * 32 + cb * 8];
    }
#pragma unroll
    for (int nf = 0; nf < 4; ++nf) {
      const int r = wc * 64 + nf * 16 + (lane & 15);
      const int cb = g ^ (r & 3);
      bfr[nf] = *(const bf16x8*)&Bsb[bufi * 4096 + r * 32 + cb * 8];
    }
#pragma unroll
    for (int mf = 0; mf < 4; ++mf)
#pragma unroll
      for (int nf = 0; nf < 4; ++nf)
        acc[mf][nf] =
            __builtin_amdgcn_mfma_f32_16x16x32_bf16(af[mf], bfr[nf], acc[mf][nf], 0, 0, 0);
  };

  const int NK = K >> 5;
  STAGE(0, 0);
  if (NK > 1) STAGE(1, 32);
  for (int it = 0; it < NK; ++it) {
    const int cur = it % 3;
    if (it + 2 < NK) {
      STAGE((it + 2) % 3, (it + 2) * 32);
      asm volatile("s_waitcnt vmcnt(8)" ::: "memory");  // cur-buffer loads done
    } else if (it + 1 < NK) {
      asm volatile("s_waitcnt vmcnt(4)" ::: "memory");
    } else {
      asm volatile("s_waitcnt vmcnt(0)" ::: "memory");
    }
    __builtin_amdgcn_s_barrier();
    __builtin_amdgcn_sched_barrier(0);
    COMPUTE(cur);
    __builtin_amdgcn_sched_barrier(0);
    __builtin_amdgcn_s_barrier();
  }

  const int r0 = g * 4, cc = lane & 15;
  if (vt != nullptr) {
    // ---- fused V^T epilogue: acc -> LDS[dh][s] (stride 136) -> coalesced Vt
    __syncthreads();  // all waves done with As/Bs region
#pragma unroll
    for (int mf = 0; mf < 4; ++mf)
#pragma unroll
      for (int i = 0; i < 4; ++i) {
        const int srow_l = wr * 64 + mf * 16 + r0 + i;  // s within tile
#pragma unroll
        for (int nf = 0; nf < 4; ++nf) {
          const int dh_l = wc * 64 + nf * 16 + cc;      // dh within tile
          pool[dh_l * 136 + srow_l] = f2bf(acc[mf][nf][i]);
        }
      }
    __syncthreads();
    const long bb = bx >> 4;             // batch
    const int s0b = (bx & 15) * 128;     // s within batch
    const int hbase = by * 2;
#pragma unroll
    for (int pass = 0; pass < 4; ++pass) {
      const int dhrow = pass * 32 + (tid >> 3);  // 0..127
      const long vrow = (bb * 16 + hbase + (dhrow >> 6)) * 64 + (dhrow & 63);
      const int cseg = (tid & 7) * 16;
      bf16x8 v0 = *(const bf16x8*)&pool[dhrow * 136 + cseg];
      bf16x8 v1 = *(const bf16x8*)&pool[dhrow * 136 + cseg + 8];
      *(bf16x8*)(vt + vrow * 2048 + s0b + cseg) = v0;
      *(bf16x8*)(vt + vrow * 2048 + s0b + cseg + 8) = v1;
    }
    return;
  }

#pragma unroll
  for (int mf = 0; mf < 4; ++mf)
#pragma unroll
    for (int i = 0; i < 4; ++i) {
      const long row = (long)bx * 128 + wr * 64 + mf * 16 + r0 + i;
#pragma unroll
      for (int nf = 0; nf < 4; ++nf) {
        const long col = (long)by * 128 + wc * 64 + nf * 16 + cc;
        float v = acc[mf][nf][i] * scale;
        if constexpr (__is_same(CT, short))
          Cb[row * (long)N + col] = f2bf(v);
        else
          Cb[row * (long)N + col] = v;
      }
    }
}

// generic batched wrapper (QM, out-proj)
template <typename CT>
__global__ __launch_bounds__(256) void gemm_bt(
    const short* __restrict__ A, const short* __restrict__ B, CT* __restrict__ C,
    int N, int K, long sA, long sB, long sC, float scale) {
  __shared__ __align__(16) short pool[24576];  // 48KB
  const int bx = blockIdx.x, by = blockIdx.y, bz = blockIdx.z;
  gemm_core<CT>(pool, A + (long)bz * sA + (long)bx * 128 * K,
                B + (long)bz * sB + (long)by * 128 * K, C + (long)bz * sC,
                N, K, scale, nullptr, bx, by);
}

// fused KV-projection + Gt, ZERO dead blocks: 1D grid of 1280 blocks.
// p in [0,1024): KV  (z = p>>9, y = (p&511)>>6, x = p&63; z==1 -> Vt epilogue)
// p in [1024,1280): Gt (zz = (p-1024)>>6, y = ((p-1024)&63)>>3, x = (p-1024)&7)
__global__ __launch_bounds__(256) void kvgt_gemm(
    const short* __restrict__ xb, const short* __restrict__ wkv,
    short* __restrict__ Kb, short* __restrict__ Vtb,
    const short* __restrict__ Mtb, const short* __restrict__ wqt,
    short* __restrict__ Gtb) {
  __shared__ __align__(16) short pool[24576];  // 48KB
  constexpr long NW = 1024l * 1024, NX = 4l * 2048 * 1024;
  const int p = blockIdx.x;
  if (p < 1024) {
    const int z = p >> 9, rem = p & 511;
    const int by = rem >> 6, bx = rem & 63;  // original (64,8) order, x fastest
    gemm_core<short>(pool, xb + (long)bx * 128 * 1024,
                     wkv + (long)z * NW + (long)by * 128 * 1024,
                     Kb + (long)z * NX, 1024, 1024, 1.0f,
                     z == 1 ? Vtb : nullptr, bx, by);
  } else {
    const int r = p - 1024;
    const int zz = r >> 6, rr = r & 63;
    const int by = rr >> 3, bx = rr & 7;     // original (8,8) order, x fastest
    gemm_core<short>(pool, Mtb + (long)zz * NW + (long)bx * 128 * 1024,
                     wqt + (long)by * 128 * 1024, Gtb + (long)zz * NW,
                     1024, 1024, 1.0f, nullptr, bx, by);
  }
}

// ---------------- flash attention (verified round-17 kernel, unchanged) ----------------
// grid (S/256, H, B); 512 threads = 8 waves; block covers 256 q-rows, each
// wave owns 32 q-rows as TWO sequential 16-q passes per staged K/V tile.

__global__ __launch_bounds__(512) void flash_attn(
    const short* __restrict__ QM, const short* __restrict__ Kb,
    const short* __restrict__ Vt, const float* __restrict__ mask,
    const int* __restrict__ mflags, short* __restrict__ AO) {
  constexpr int S = 2048, D = 1024, NT = S / 64;
  constexpr float LOG2E = 1.44269504088896f;
  constexpr float CLIP = 50.0f * LOG2E;
  __shared__ __align__(16) short Ks[2][64 * 64];
  __shared__ __align__(16) short Vs[2][64 * 64];
  __shared__ __align__(16) short Ps[8][16 * 64];
  const int tid = threadIdx.x;
  const int w = tid >> 6, lane = tid & 63;
  const int q = lane & 15, g = lane >> 4;
  const int q0 = blockIdx.x * 256;
  const int h = blockIdx.y;
  const long b = blockIdx.z;

  const short* QMb = QM + (b * S) * D + h * 64;
  const short* Kbp = Kb + (b * S) * D + h * 64;
  const short* Vtp = Vt + ((b * 16 + h) * 64) * S;
  const int qw = q0 + w * 32;  // this wave's 32 q-rows

  bf16x8 qf0[2], qf1[2];
#pragma unroll
  for (int ks = 0; ks < 2; ++ks) {
    qf0[ks] = *(const bf16x8*)(QMb + (long)(qw + q) * D + ks * 32 + g * 8);
    qf1[ks] = *(const bf16x8*)(QMb + (long)(qw + 16 + q) * D + ks * 32 + g * 8);
  }

  bf16x8 onesf;
#pragma unroll
  for (int j = 0; j < 8; ++j) onesf[j] = (__bf16)1.0f;

  f32x4 accA[4], accB[4];
#pragma unroll
  for (int f = 0; f < 4; ++f) {
    accA[f] = {0.f, 0.f, 0.f, 0.f};
    accB[f] = {0.f, 0.f, 0.f, 0.f};
  }
  f32x4 acc_lA = {0.f, 0.f, 0.f, 0.f};
  f32x4 acc_lB = {0.f, 0.f, 0.f, 0.f};

  const int srow8 = lane >> 3;
  const int scol8 = ((lane & 7) ^ (srow8 & 7)) * 8;
  short* Pw = &Ps[w][0];
  const int psw = (q & 7) << 3;

  auto STAGE = [&](int bufi, int t0) {
    const int row = w * 8 + srow8;
    gload_lds16(Kbp + (long)(t0 + row) * D + scol8, &Ks[bufi][w * 512]);
    gload_lds16(Vtp + (long)row * S + t0 + scol8, &Vs[bufi][w * 512]);
  };

  auto COMPUTE_U = [&](int bufi, int t0, int qrow, const bf16x8 (&qf)[2],
                       f32x4 (&acc)[4], f32x4& acc_l) {
    f32x4 sacc[4];
#pragma unroll
    for (int nf = 0; nf < 4; ++nf) sacc[nf] = {0.f, 0.f, 0.f, 0.f};
    __builtin_amdgcn_s_setprio(1);
#pragma unroll
    for (int ks = 0; ks < 2; ++ks) {
#pragma unroll
      for (int nf = 0; nf < 4; ++nf) {
        const int r = nf * 16 + q;
        const int blk = (ks * 4 + g) ^ (r & 7);
        bf16x8 kf = *(const bf16x8*)&Ks[bufi][r * 64 + blk * 8];
        sacc[nf] = __builtin_amdgcn_mfma_f32_16x16x32_bf16(kf, qf[ks], sacc[nf], 0, 0, 0);
      }
    }
    __builtin_amdgcn_s_setprio(0);

    float pv[4][4];
    const int* flagrowU = mflags + (qrow >> 6) * 32;
    if (__builtin_expect(flagrowU[t0 >> 6], 0)) {
      const float* mrow = mask + (long)(qrow + q) * S + t0;
#pragma unroll
      for (int nf = 0; nf < 4; ++nf) {
        float4 mv = *(const float4*)(mrow + nf * 16 + 4 * g);
        const float* mp = &mv.x;
#pragma unroll
        for (int i = 0; i < 4; ++i)
          pv[nf][i] = exp2_fast(
              __builtin_amdgcn_fmed3f(sacc[nf][i], -CLIP, CLIP) + LOG2E * mp[i]);
      }
    } else {
#pragma unroll
      for (int nf = 0; nf < 4; ++nf)
#pragma unroll
        for (int i = 0; i < 4; ++i)
          pv[nf][i] = exp2_fast(__builtin_amdgcn_fmed3f(sacc[nf][i], -CLIP, CLIP));
    }
#pragma unroll
    for (int nf = 0; nf < 4; ++nf) {
      uint2 u;
      u.x = cvt_pk_bf16(pv[nf][0], pv[nf][1]);
      u.y = cvt_pk_bf16(pv[nf][2], pv[nf][3]);
      *(uint2*)&Pw[q * 64 + ((nf * 16 + 4 * g) ^ psw)] = u;
    }

    mem_fence_compiler();  // P stores (uint2) precede P loads (bf16x8)

    __builtin_amdgcn_s_setprio(1);
#pragma unroll
    for (int ts = 0; ts < 2; ++ts) {
      bf16x8 pfr = *(const bf16x8*)&Pw[q * 64 + ((ts * 32 + 8 * g) ^ psw)];
#pragma unroll
      for (int f = 0; f < 4; ++f) {
        const int vr = f * 16 + q;
        const int vblk = (ts * 4 + g) ^ (vr & 7);
        bf16x8 vf = *(const bf16x8*)&Vs[bufi][vr * 64 + vblk * 8];
        acc[f] = __builtin_amdgcn_mfma_f32_16x16x32_bf16(vf, pfr, acc[f], 0, 0, 0);
      }
      acc_l = __builtin_amdgcn_mfma_f32_16x16x32_bf16(onesf, pfr, acc_l, 0, 0, 0);
    }
    __builtin_amdgcn_s_setprio(0);
    mem_fence_compiler();  // P loads precede the next pass's P stores
  };

  STAGE(0, 0);
  for (int it = 0; it < NT; ++it) {
    const int cur = it & 1;
    if (it + 1 < NT) {
      STAGE(cur ^ 1, (it + 1) * 64);
      asm volatile("s_waitcnt vmcnt(2)" ::: "memory");  // cur-buffer loads done
    } else {
      asm volatile("s_waitcnt vmcnt(0)" ::: "memory");
    }
    __builtin_amdgcn_s_barrier();
    __builtin_amdgcn_sched_barrier(0);
    COMPUTE_U(cur, it * 64, qw, qf0, accA, acc_lA);
    COMPUTE_U(cur, it * 64, qw + 16, qf1, accB, acc_lB);
    __builtin_amdgcn_sched_barrier(0);
    __builtin_amdgcn_s_barrier();
  }

  // epilogue per pass: normalize, transpose O^T -> O via wave-private LDS
  const int qr = lane >> 2, c0 = (lane & 3) * 16;
  short* AOp = AO + (b * S) * D + h * 64;
#pragma unroll
  for (int u = 0; u < 2; ++u) {
    const f32x4* acc = (u == 0) ? accA : accB;
    const float inv = 1.0f / ((u == 0) ? acc_lA[0] : acc_lB[0]);
#pragma unroll
    for (int f = 0; f < 4; ++f) {
      uint2 uu;
      uu.x = cvt_pk_bf16(acc[f][0] * inv, acc[f][1] * inv);
      uu.y = cvt_pk_bf16(acc[f][2] * inv, acc[f][3] * inv);
      *(uint2*)&Pw[q * 64 + ((f * 16 + 4 * g) ^ psw)] = uu;
    }
    mem_fence_compiler();  // O stores (uint2) precede transpose loads (bf16x8)
#pragma unroll
    for (int r2 = 0; r2 < 2; ++r2) {
      const int cc2 = c0 + r2 * 8;
      bf16x8 ov = *(const bf16x8*)&Pw[qr * 64 + (cc2 ^ ((qr & 7) << 3))];
      *(bf16x8*)(AOp + (long)(qw + u * 16 + qr) * D + cc2) = ov;
    }
    mem_fence_compiler();  // transpose loads precede next pass's O stores
  }
}

// ---------------- launch ----------------

extern "C" void kernel_launch(void* const* d_in, const int* in_sizes, int n_in,
                              void* d_out, int out_size, void* d_ws, size_t ws_size,
                              hipStream_t stream) {
  const float* x = (const float*)d_in[0];
  const float* M = (const float*)d_in[1];
  const float* mask = (const float*)d_in[2];
  const float* Wq = (const float*)d_in[3];
  const float* Wk = (const float*)d_in[4];
  const float* Wv = (const float*)d_in[5];
  const float* Wo = (const float*)d_in[6];
  float* out = (float*)d_out;

  constexpr long S = 2048, D = 1024;
  constexpr long NX = 4 * S * D;  // 8388608
  constexpr long NW = D * D;      // 1048576
  constexpr float C1 = 0.125f * 1.44269504088896f;  // 1/sqrt(64) * log2(e)

  short* p = (short*)d_ws;
  short* xb = p;   p += NX;
  short* wkb = p;  p += NW;  // wk, wv contiguous (stride NW) for batched K,V proj
  short* wvb = p;  p += NW;
  short* wob = p;  p += NW;
  short* wqt = p;  p += NW;       // Wq^T  [c][d]
  short* Mtb = p;  p += 4 * NW;   // M^T   [b][e][d]
  short* Gtb = p;  p += 4 * NW;   // G^T = M^T Wq  [b][e][c]
  short* Kb = p;   p += NX;       // K (row-major)
  short* QMb = p;  p += NX;
  short* Vtb = p;  p += NX;       // V^T [b*16+h][dh][s] (written by fused epilogue)
  int* flags = (int*)p;  p += 2048;  // 32x32 tile flags (4KB)
  short* AOb = Mtb;  // Mt+Gt region (8*NW == NX shorts) dead after QM -> reuse for AO

  cvt_f32_bf16<<<NX / 2048, 256, 0, stream>>>(x, xb, NX);
  cvt3_f32_bf16<<<1536, 256, 0, stream>>>(Wk, wkb, Wv, wvb, Wo, wob);
  cvtT5<<<dim3(16, 16, 5), 256, 0, stream>>>(Wq, wqt, M, Mtb);  // Wq^T + M^T
  mask_flags<<<dim3(32, 32), 256, 0, stream>>>(mask, flags);

  // K,V projections (V stores transposed to Vtb) + independent G^T GEMM in
  // ONE 1280-block launch, zero dead blocks
  kvgt_gemm<<<1280, 256, 0, stream>>>(xb, wkb, Kb, Vtb, Mtb, wqt, Gtb);
  // QM[b][s][e] = C1 * sum_c x[b][s][c] * Gt[b][e][c]  (fused Q-proj + bilinear,
  // pre-scaled into the log2-softmax domain for flash)
  gemm_bt<short><<<dim3(16, 8, 4), 256, 0, stream>>>(xb, Gtb, QMb, 1024, 1024,
                                                     S * D, NW, S * D, C1);
  flash_attn<<<dim3(8, 16, 4), 512, 0, stream>>>(QMb, Kb, Vtb, mask, flags, AOb);
  // out = AO @ Wo^T (f32 store)
  gemm_bt<float><<<dim3(64, 8, 1), 256, 0, stream>>>(AOb, wob, out, 1024, 1024,
                                                     0, 0, 0, 1.0f);
}

// Round 21
// 214.212 us; speedup vs baseline: 1.0890x; 1.0191x over previous
//
#include <hip/hip_runtime.h>
#include <cstdint>

typedef __attribute__((ext_vector_type(8))) short short8;
typedef __attribute__((ext_vector_type(8))) __bf16 bf16x8;
typedef __attribute__((ext_vector_type(4))) float f32x4;

__device__ __forceinline__ uint32_t cvt_pk_bf16(float lo, float hi) {
  uint32_t r;
  asm("v_cvt_pk_bf16_f32 %0, %1, %2" : "=v"(r) : "v"(lo), "v"(hi));
  return r;
}

__device__ __forceinline__ short f2bf(float f) {  // 1-op RNE via cvt_pk
  return (short)cvt_pk_bf16(f, f);
}

__device__ __forceinline__ float exp2_fast(float x) {
  return __builtin_amdgcn_exp2f(x);  // v_exp_f32 (native 2^x)
}

// compiler-level memory fence (no instruction emitted)
__device__ __forceinline__ void mem_fence_compiler() {
  asm volatile("" ::: "memory");
}

__device__ __forceinline__ void gload_lds16(const void* g, void* l) {
  __builtin_amdgcn_global_load_lds(
      (const __attribute__((address_space(1))) void*)(uintptr_t)g,
      (__attribute__((address_space(3))) void*)(uint32_t)(uintptr_t)l,
      16, 0, 0);
}

// ---------------- fused preprocessing: ONE launch, zero dead blocks ----------------
// p in [0,4096):      x f32->bf16 (4096 blocks)
// p in [4096,5632):   Wk/Wv/Wo f32->bf16 (512 blocks each)
// p in [5632,6912):   transpose-convert Wq^T (z=0) + M^T (z=1..4), 256 blocks each
// p in [6912,7936):   mask tile flags (32x32 tiles)
// Each block runs exactly one verified body; LDS = max of branches (8.3KB).

__global__ __launch_bounds__(256) void preproc_all(
    const float* __restrict__ x, short* __restrict__ xb,
    const float* __restrict__ Wk, short* __restrict__ wkb,
    const float* __restrict__ Wv, short* __restrict__ wvb,
    const float* __restrict__ Wo, short* __restrict__ wob,
    const float* __restrict__ Wq, short* __restrict__ wqt,
    const float* __restrict__ M, short* __restrict__ Mt,
    const float* __restrict__ mask, int* __restrict__ flags) {
  __shared__ __align__(16) short t[64][65];
  __shared__ int fshare;
  const int p = blockIdx.x;
  const int tid = threadIdx.x;

  if (p < 5632) {
    // ---- flat f32 -> bf16 conversion (x or one of Wk/Wv/Wo)
    const float* s;
    short* d;
    long blk;
    if (p < 4096) {
      s = x; d = xb; blk = p;
    } else {
      const int tsel = (p - 4096) >> 9;
      s = tsel == 0 ? Wk : (tsel == 1 ? Wv : Wo);
      d = tsel == 0 ? wkb : (tsel == 1 ? wvb : wob);
      blk = (p - 4096) & 511;
    }
    const long i = (blk * 256 + tid) * 8;
    const float4 a = *(const float4*)(s + i);
    const float4 b = *(const float4*)(s + i + 4);
    uint4 o;
    o.x = cvt_pk_bf16(a.x, a.y);
    o.y = cvt_pk_bf16(a.z, a.w);
    o.z = cvt_pk_bf16(b.x, b.y);
    o.w = cvt_pk_bf16(b.z, b.w);
    *(uint4*)(d + i) = o;
  } else if (p < 6912) {
    // ---- transpose-convert 64x64 tile (z==0 -> Wq^T, z>=1 -> M[z-1]^T)
    const int r = p - 5632;
    const int z = r >> 8, rr = r & 255;
    const int bx = rr & 15, by = rr >> 4;  // x fastest (original grid order)
    const float* src = z == 0 ? Wq : M + (long)(z - 1) * 1024 * 1024;
    short* dst = z == 0 ? wqt : Mt + (long)(z - 1) * 1024 * 1024;
    const int d0 = bx * 64, e0 = by * 64;
#pragma unroll
    for (int k = 0; k < 16; ++k) {
      int idx = k * 256 + tid; int rr2 = idx >> 6, c = idx & 63;
      t[rr2][c] = f2bf(src[(long)(d0 + rr2) * 1024 + e0 + c]);
    }
    __syncthreads();
#pragma unroll
    for (int k = 0; k < 16; ++k) {
      int idx = k * 256 + tid; int rr2 = idx >> 6, c = idx & 63;
      dst[(long)(e0 + rr2) * 1024 + d0 + c] = t[c][rr2];
    }
  } else {
    // ---- mask tile flags: flags[qt*32+tt] = any nonzero in 64x64 tile
    const int r = p - 6912;
    const int qt = r & 31, tt = r >> 5;
    if (tid == 0) fshare = 0;
    __syncthreads();
    const float* base = mask + (long)qt * 64 * 2048 + tt * 64;
    const int rr2 = tid >> 2, c = (tid & 3) * 16;
    bool nz = false;
#pragma unroll
    for (int k = 0; k < 4; ++k) {
      float4 v = *(const float4*)(base + (long)rr2 * 2048 + c + k * 4);
      nz = nz | (v.x != 0.f) | (v.y != 0.f) | (v.z != 0.f) | (v.w != 0.f);
    }
    if (nz) fshare = 1;
    __syncthreads();
    if (tid == 0) flags[qt * 32 + tt] = fshare;
  }
}

// ---------------- GEMM core: 128x128 tile = scale * A * B^T (bf16 in, f32 acc) ----------
// BK=32, TRIPLE-buffered (prefetch depth 2, steady vmcnt(8)). Verified
// 2-barrier skeleton (rounds 8-20). If vt != nullptr the epilogue stores
// TRANSPOSED into vt[(bx>>4)*16+by*2+..][dh][s] via an LDS round-trip
// (stride 136 shorts, 2-way-conflict-free) instead of writing C.

template <typename CT>
__device__ __forceinline__ void gemm_core(
    short* pool, const short* __restrict__ Ab, const short* __restrict__ Bb,
    CT* __restrict__ Cb, int N, int K, float scale, short* __restrict__ vt,
    int bx, int by) {
  short* Asb = pool;
  short* Bsb = pool + 12288;
  const int tid = threadIdx.x;
  const int w = tid >> 6, lane = tid & 63;
  const int wr = w >> 1, wc = w & 1;
  const int g = lane >> 4;

  f32x4 acc[4][4];
#pragma unroll
  for (int i = 0; i < 4; ++i)
#pragma unroll
    for (int j = 0; j < 4; ++j) acc[i][j] = {0.f, 0.f, 0.f, 0.f};

  const int srow = lane >> 2;                      // row within 16-row chunk
  const int scol = ((lane & 3) ^ (srow & 3)) * 8;  // pre-swizzled source col (shorts)

  auto STAGE = [&](int bufi, int k0) {
#pragma unroll
    for (int c = 0; c < 2; ++c) {
      const int chunk = w * 2 + c;
      const long gr = (long)(chunk * 16 + srow);
      gload_lds16(Ab + gr * K + k0 + scol, Asb + bufi * 4096 + chunk * 512);
      gload_lds16(Bb + gr * K + k0 + scol, Bsb + bufi * 4096 + chunk * 512);
    }
  };

  auto COMPUTE = [&](int bufi) {
    bf16x8 af[4], bfr[4];
#pragma unroll
    for (int mf = 0; mf < 4; ++mf) {
      const int r = wr * 64 + mf * 16 + (lane & 15);
      const int cb = g ^ (r & 3);
      af[mf] = *(const bf16x8*)&Asb[bufi * 4096 + r * 32 + cb * 8];
    }
#pragma unroll
    for (int nf = 0; nf < 4; ++nf) {
      const int r = wc * 64 + nf * 16 + (lane & 15);
      const int cb = g ^ (r & 3);
      bfr[nf] = *(const bf16x8*)&Bsb[bufi * 4096 + r * 32 + cb * 8];
    }
#pragma unroll
    for (int mf = 0; mf < 4; ++mf)
#pragma unroll
      for (int nf = 0; nf < 4; ++nf)
        acc[mf][nf] =
            __builtin_amdgcn_mfma_f32_16x16x32_bf16(af[mf], bfr[nf], acc[mf][nf], 0, 0, 0);
  };

  const int NK = K >> 5;
  STAGE(0, 0);
  if (NK > 1) STAGE(1, 32);
  for (int it = 0; it < NK; ++it) {
    const int cur = it % 3;
    if (it + 2 < NK) {
      STAGE((it + 2) % 3, (it + 2) * 32);
      asm volatile("s_waitcnt vmcnt(8)" ::: "memory");  // cur-buffer loads done
    } else if (it + 1 < NK) {
      asm volatile("s_waitcnt vmcnt(4)" ::: "memory");
    } else {
      asm volatile("s_waitcnt vmcnt(0)" ::: "memory");
    }
    __builtin_amdgcn_s_barrier();
    __builtin_amdgcn_sched_barrier(0);
    COMPUTE(cur);
    __builtin_amdgcn_sched_barrier(0);
    __builtin_amdgcn_s_barrier();
  }

  const int r0 = g * 4, cc = lane & 15;
  if (vt != nullptr) {
    // ---- fused V^T epilogue: acc -> LDS[dh][s] (stride 136) -> coalesced Vt
    __syncthreads();  // all waves done with As/Bs region
#pragma unroll
    for (int mf = 0; mf < 4; ++mf)
#pragma unroll
      for (int i = 0; i < 4; ++i) {
        const int srow_l = wr * 64 + mf * 16 + r0 + i;  // s within tile
#pragma unroll
        for (int nf = 0; nf < 4; ++nf) {
          const int dh_l = wc * 64 + nf * 16 + cc;      // dh within tile
          pool[dh_l * 136 + srow_l] = f2bf(acc[mf][nf][i]);
        }
      }
    __syncthreads();
    const long bb = bx >> 4;             // batch
    const int s0b = (bx & 15) * 128;     // s within batch
    const int hbase = by * 2;
#pragma unroll
    for (int pass = 0; pass < 4; ++pass) {
      const int dhrow = pass * 32 + (tid >> 3);  // 0..127
      const long vrow = (bb * 16 + hbase + (dhrow >> 6)) * 64 + (dhrow & 63);
      const int cseg = (tid & 7) * 16;
      bf16x8 v0 = *(const bf16x8*)&pool[dhrow * 136 + cseg];
      bf16x8 v1 = *(const bf16x8*)&pool[dhrow * 136 + cseg + 8];
      *(bf16x8*)(vt + vrow * 2048 + s0b + cseg) = v0;
      *(bf16x8*)(vt + vrow * 2048 + s0b + cseg + 8) = v1;
    }
    return;
  }

#pragma unroll
  for (int mf = 0; mf < 4; ++mf)
#pragma unroll
    for (int i = 0; i < 4; ++i) {
      const long row = (long)bx * 128 + wr * 64 + mf * 16 + r0 + i;
#pragma unroll
      for (int nf = 0; nf < 4; ++nf) {
        const long col = (long)by * 128 + wc * 64 + nf * 16 + cc;
        float v = acc[mf][nf][i] * scale;
        if constexpr (__is_same(CT, short))
          Cb[row * (long)N + col] = f2bf(v);
        else
          Cb[row * (long)N + col] = v;
      }
    }
}

// generic batched wrapper (QM, out-proj)
template <typename CT>
__global__ __launch_bounds__(256) void gemm_bt(
    const short* __restrict__ A, const short* __restrict__ B, CT* __restrict__ C,
    int N, int K, long sA, long sB, long sC, float scale) {
  __shared__ __align__(16) short pool[24576];  // 48KB
  const int bx = blockIdx.x, by = blockIdx.y, bz = blockIdx.z;
  gemm_core<CT>(pool, A + (long)bz * sA + (long)bx * 128 * K,
                B + (long)bz * sB + (long)by * 128 * K, C + (long)bz * sC,
                N, K, scale, nullptr, bx, by);
}

// fused KV-projection + Gt, ZERO dead blocks: 1D grid of 1280 blocks.
// p in [0,1024): KV  (z = p>>9, y = (p&511)>>6, x = p&63; z==1 -> Vt epilogue)
// p in [1024,1280): Gt (zz = (p-1024)>>6, y = ((p-1024)&63)>>3, x = (p-1024)&7)
__global__ __launch_bounds__(256) void kvgt_gemm(
    const short* __restrict__ xb, const short* __restrict__ wkv,
    short* __restrict__ Kb, short* __restrict__ Vtb,
    const short* __restrict__ Mtb, const short* __restrict__ wqt,
    short* __restrict__ Gtb) {
  __shared__ __align__(16) short pool[24576];  // 48KB
  constexpr long NW = 1024l * 1024, NX = 4l * 2048 * 1024;
  const int p = blockIdx.x;
  if (p < 1024) {
    const int z = p >> 9, rem = p & 511;
    const int by = rem >> 6, bx = rem & 63;  // original (64,8) order, x fastest
    gemm_core<short>(pool, xb + (long)bx * 128 * 1024,
                     wkv + (long)z * NW + (long)by * 128 * 1024,
                     Kb + (long)z * NX, 1024, 1024, 1.0f,
                     z == 1 ? Vtb : nullptr, bx, by);
  } else {
    const int r = p - 1024;
    const int zz = r >> 6, rr = r & 63;
    const int by = rr >> 3, bx = rr & 7;     // original (8,8) order, x fastest
    gemm_core<short>(pool, Mtb + (long)zz * NW + (long)bx * 128 * 1024,
                     wqt + (long)by * 128 * 1024, Gtb + (long)zz * NW,
                     1024, 1024, 1.0f, nullptr, bx, by);
  }
}

// ---------------- flash attention (verified round-17 kernel, unchanged) ----------------
// grid (S/256, H, B); 512 threads = 8 waves; block covers 256 q-rows, each
// wave owns 32 q-rows as TWO sequential 16-q passes per staged K/V tile.

__global__ __launch_bounds__(512) void flash_attn(
    const short* __restrict__ QM, const short* __restrict__ Kb,
    const short* __restrict__ Vt, const float* __restrict__ mask,
    const int* __restrict__ mflags, short* __restrict__ AO) {
  constexpr int S = 2048, D = 1024, NT = S / 64;
  constexpr float LOG2E = 1.44269504088896f;
  constexpr float CLIP = 50.0f * LOG2E;
  __shared__ __align__(16) short Ks[2][64 * 64];
  __shared__ __align__(16) short Vs[2][64 * 64];
  __shared__ __align__(16) short Ps[8][16 * 64];
  const int tid = threadIdx.x;
  const int w = tid >> 6, lane = tid & 63;
  const int q = lane & 15, g = lane >> 4;
  const int q0 = blockIdx.x * 256;
  const int h = blockIdx.y;
  const long b = blockIdx.z;

  const short* QMb = QM + (b * S) * D + h * 64;
  const short* Kbp = Kb + (b * S) * D + h * 64;
  const short* Vtp = Vt + ((b * 16 + h) * 64) * S;
  const int qw = q0 + w * 32;  // this wave's 32 q-rows

  bf16x8 qf0[2], qf1[2];
#pragma unroll
  for (int ks = 0; ks < 2; ++ks) {
    qf0[ks] = *(const bf16x8*)(QMb + (long)(qw + q) * D + ks * 32 + g * 8);
    qf1[ks] = *(const bf16x8*)(QMb + (long)(qw + 16 + q) * D + ks * 32 + g * 8);
  }

  bf16x8 onesf;
#pragma unroll
  for (int j = 0; j < 8; ++j) onesf[j] = (__bf16)1.0f;

  f32x4 accA[4], accB[4];
#pragma unroll
  for (int f = 0; f < 4; ++f) {
    accA[f] = {0.f, 0.f, 0.f, 0.f};
    accB[f] = {0.f, 0.f, 0.f, 0.f};
  }
  f32x4 acc_lA = {0.f, 0.f, 0.f, 0.f};
  f32x4 acc_lB = {0.f, 0.f, 0.f, 0.f};

  const int srow8 = lane >> 3;
  const int scol8 = ((lane & 7) ^ (srow8 & 7)) * 8;
  short* Pw = &Ps[w][0];
  const int psw = (q & 7) << 3;

  auto STAGE = [&](int bufi, int t0) {
    const int row = w * 8 + srow8;
    gload_lds16(Kbp + (long)(t0 + row) * D + scol8, &Ks[bufi][w * 512]);
    gload_lds16(Vtp + (long)row * S + t0 + scol8, &Vs[bufi][w * 512]);
  };

  auto COMPUTE_U = [&](int bufi, int t0, int qrow, const bf16x8 (&qf)[2],
                       f32x4 (&acc)[4], f32x4& acc_l) {
    f32x4 sacc[4];
#pragma unroll
    for (int nf = 0; nf < 4; ++nf) sacc[nf] = {0.f, 0.f, 0.f, 0.f};
    __builtin_amdgcn_s_setprio(1);
#pragma unroll
    for (int ks = 0; ks < 2; ++ks) {
#pragma unroll
      for (int nf = 0; nf < 4; ++nf) {
        const int r = nf * 16 + q;
        const int blk = (ks * 4 + g) ^ (r & 7);
        bf16x8 kf = *(const bf16x8*)&Ks[bufi][r * 64 + blk * 8];
        sacc[nf] = __builtin_amdgcn_mfma_f32_16x16x32_bf16(kf, qf[ks], sacc[nf], 0, 0, 0);
      }
    }
    __builtin_amdgcn_s_setprio(0);

    float pv[4][4];
    const int* flagrowU = mflags + (qrow >> 6) * 32;
    if (__builtin_expect(flagrowU[t0 >> 6], 0)) {
      const float* mrow = mask + (long)(qrow + q) * S + t0;
#pragma unroll
      for (int nf = 0; nf < 4; ++nf) {
        float4 mv = *(const float4*)(mrow + nf * 16 + 4 * g);
        const float* mp = &mv.x;
#pragma unroll
        for (int i = 0; i < 4; ++i)
          pv[nf][i] = exp2_fast(
              __builtin_amdgcn_fmed3f(sacc[nf][i], -CLIP, CLIP) + LOG2E * mp[i]);
      }
    } else {
#pragma unroll
      for (int nf = 0; nf < 4; ++nf)
#pragma unroll
        for (int i = 0; i < 4; ++i)
          pv[nf][i] = exp2_fast(__builtin_amdgcn_fmed3f(sacc[nf][i], -CLIP, CLIP));
    }
#pragma unroll
    for (int nf = 0; nf < 4; ++nf) {
      uint2 u;
      u.x = cvt_pk_bf16(pv[nf][0], pv[nf][1]);
      u.y = cvt_pk_bf16(pv[nf][2], pv[nf][3]);
      *(uint2*)&Pw[q * 64 + ((nf * 16 + 4 * g) ^ psw)] = u;
    }

    mem_fence_compiler();  // P stores (uint2) precede P loads (bf16x8)

    __builtin_amdgcn_s_setprio(1);
#pragma unroll
    for (int ts = 0; ts < 2; ++ts) {
      bf16x8 pfr = *(const bf16x8*)&Pw[q * 64 + ((ts * 32 + 8 * g) ^ psw)];
#pragma unroll
      for (int f = 0; f < 4; ++f) {
        const int vr = f * 16 + q;
        const int vblk = (ts * 4 + g) ^ (vr & 7);
        bf16x8 vf = *(const bf16x8*)&Vs[bufi][vr * 64 + vblk * 8];
        acc[f] = __builtin_amdgcn_mfma_f32_16x16x32_bf16(vf, pfr, acc[f], 0, 0, 0);
      }
      acc_l = __builtin_amdgcn_mfma_f32_16x16x32_bf16(onesf, pfr, acc_l, 0, 0, 0);
    }
    __builtin_amdgcn_s_setprio(0);
    mem_fence_compiler();  // P loads precede the next pass's P stores
  };

  STAGE(0, 0);
  for (int it = 0; it < NT; ++it) {
    const int cur = it & 1;
    if (it + 1 < NT) {
      STAGE(cur ^ 1, (it + 1) * 64);
      asm volatile("s_waitcnt vmcnt(2)" ::: "memory");  // cur-buffer loads done
    } else {
      asm volatile("s_waitcnt vmcnt(0)" ::: "memory");
    }
    __builtin_amdgcn_s_barrier();
    __builtin_amdgcn_sched_barrier(0);
    COMPUTE_U(cur, it * 64, qw, qf0, accA, acc_lA);
    COMPUTE_U(cur, it * 64, qw + 16, qf1, accB, acc_lB);
    __builtin_amdgcn_sched_barrier(0);
    __builtin_amdgcn_s_barrier();
  }

  // epilogue per pass: normalize, transpose O^T -> O via wave-private LDS
  const int qr = lane >> 2, c0 = (lane & 3) * 16;
  short* AOp = AO + (b * S) * D + h * 64;
#pragma unroll
  for (int u = 0; u < 2; ++u) {
    const f32x4* acc = (u == 0) ? accA : accB;
    const float inv = 1.0f / ((u == 0) ? acc_lA[0] : acc_lB[0]);
#pragma unroll
    for (int f = 0; f < 4; ++f) {
      uint2 uu;
      uu.x = cvt_pk_bf16(acc[f][0] * inv, acc[f][1] * inv);
      uu.y = cvt_pk_bf16(acc[f][2] * inv, acc[f][3] * inv);
      *(uint2*)&Pw[q * 64 + ((f * 16 + 4 * g) ^ psw)] = uu;
    }
    mem_fence_compiler();  // O stores (uint2) precede transpose loads (bf16x8)
#pragma unroll
    for (int r2 = 0; r2 < 2; ++r2) {
      const int cc2 = c0 + r2 * 8;
      bf16x8 ov = *(const bf16x8*)&Pw[qr * 64 + (cc2 ^ ((qr & 7) << 3))];
      *(bf16x8*)(AOp + (long)(qw + u * 16 + qr) * D + cc2) = ov;
    }
    mem_fence_compiler();  // transpose loads precede next pass's O stores
  }
}

// ---------------- launch ----------------

extern "C" void kernel_launch(void* const* d_in, const int* in_sizes, int n_in,
                              void* d_out, int out_size, void* d_ws, size_t ws_size,
                              hipStream_t stream) {
  const float* x = (const float*)d_in[0];
  const float* M = (const float*)d_in[1];
  const float* mask = (const float*)d_in[2];
  const float* Wq = (const float*)d_in[3];
  const float* Wk = (const float*)d_in[4];
  const float* Wv = (const float*)d_in[5];
  const float* Wo = (const float*)d_in[6];
  float* out = (float*)d_out;

  constexpr long S = 2048, D = 1024;
  constexpr long NX = 4 * S * D;  // 8388608
  constexpr long NW = D * D;      // 1048576
  constexpr float C1 = 0.125f * 1.44269504088896f;  // 1/sqrt(64) * log2(e)

  short* p = (short*)d_ws;
  short* xb = p;   p += NX;
  short* wkb = p;  p += NW;  // wk, wv contiguous (stride NW) for batched K,V proj
  short* wvb = p;  p += NW;
  short* wob = p;  p += NW;
  short* wqt = p;  p += NW;       // Wq^T  [c][d]
  short* Mtb = p;  p += 4 * NW;   // M^T   [b][e][d]
  short* Gtb = p;  p += 4 * NW;   // G^T = M^T Wq  [b][e][c]
  short* Kb = p;   p += NX;       // K (row-major)
  short* QMb = p;  p += NX;
  short* Vtb = p;  p += NX;       // V^T [b*16+h][dh][s] (written by fused epilogue)
  int* flags = (int*)p;  p += 2048;  // 32x32 tile flags (4KB)
  short* AOb = Mtb;  // Mt+Gt region (8*NW == NX shorts) dead after QM -> reuse for AO

  // ALL preprocessing (x/Wk/Wv/Wo cvt + Wq^T/M^T transpose + mask flags) in
  // ONE 7936-block launch, zero dead blocks
  preproc_all<<<7936, 256, 0, stream>>>(x, xb, Wk, wkb, Wv, wvb, Wo, wob,
                                        Wq, wqt, M, Mtb, mask, flags);

  // K,V projections (V stores transposed to Vtb) + independent G^T GEMM in
  // ONE 1280-block launch, zero dead blocks
  kvgt_gemm<<<1280, 256, 0, stream>>>(xb, wkb, Kb, Vtb, Mtb, wqt, Gtb);
  // QM[b][s][e] = C1 * sum_c x[b][s][c] * Gt[b][e][c]  (fused Q-proj + bilinear,
  // pre-scaled into the log2-softmax domain for flash)
  gemm_bt<short><<<dim3(16, 8, 4), 256, 0, stream>>>(xb, Gtb, QMb, 1024, 1024,
                                                     S * D, NW, S * D, C1);
  flash_attn<<<dim3(8, 16, 4), 512, 0, stream>>>(QMb, Kb, Vtb, mask, flags, AOb);
  // out = AO @ Wo^T (f32 store)
  gemm_bt<float><<<dim3(64, 8, 1), 256, 0, stream>>>(AOb, wob, out, 1024, 1024,
                                                     0, 0, 0, 1.0f);
}

// Round 22
// 209.588 us; speedup vs baseline: 1.1130x; 1.0221x over previous
//
#include <hip/hip_runtime.h>
#include <cstdint>

typedef __attribute__((ext_vector_type(8))) short short8;
typedef __attribute__((ext_vector_type(8))) __bf16 bf16x8;
typedef __attribute__((ext_vector_type(4))) float f32x4;

__device__ __forceinline__ uint32_t cvt_pk_bf16(float lo, float hi) {
  uint32_t r;
  asm("v_cvt_pk_bf16_f32 %0, %1, %2" : "=v"(r) : "v"(lo), "v"(hi));
  return r;
}

__device__ __forceinline__ short f2bf(float f) {  // 1-op RNE via cvt_pk
  return (short)cvt_pk_bf16(f, f);
}

__device__ __forceinline__ float exp2_fast(float x) {
  return __builtin_amdgcn_exp2f(x);  // v_exp_f32 (native 2^x)
}

// compiler-level memory fence (no instruction emitted)
__device__ __forceinline__ void mem_fence_compiler() {
  asm volatile("" ::: "memory");
}

__device__ __forceinline__ void gload_lds16(const void* g, void* l) {
  __builtin_amdgcn_global_load_lds(
      (const __attribute__((address_space(1))) void*)(uintptr_t)g,
      (__attribute__((address_space(3))) void*)(uint32_t)(uintptr_t)l,
      16, 0, 0);
}

// ---------------- fused preprocessing: ONE launch, zero dead blocks ----------------
// p in [0,4096):      x f32->bf16 (4096 blocks)
// p in [4096,5632):   Wk/Wv/Wo f32->bf16 (512 blocks each)
// p in [5632,6912):   transpose-convert Wq^T (z=0) + M^T (z=1..4), 256 blocks each
// p in [6912,7936):   mask tile flags (32x32 tiles)

__global__ __launch_bounds__(256) void preproc_all(
    const float* __restrict__ x, short* __restrict__ xb,
    const float* __restrict__ Wk, short* __restrict__ wkb,
    const float* __restrict__ Wv, short* __restrict__ wvb,
    const float* __restrict__ Wo, short* __restrict__ wob,
    const float* __restrict__ Wq, short* __restrict__ wqt,
    const float* __restrict__ M, short* __restrict__ Mt,
    const float* __restrict__ mask, int* __restrict__ flags) {
  __shared__ __align__(16) short t[64][65];
  __shared__ int fshare;
  const int p = blockIdx.x;
  const int tid = threadIdx.x;

  if (p < 5632) {
    const float* s;
    short* d;
    long blk;
    if (p < 4096) {
      s = x; d = xb; blk = p;
    } else {
      const int tsel = (p - 4096) >> 9;
      s = tsel == 0 ? Wk : (tsel == 1 ? Wv : Wo);
      d = tsel == 0 ? wkb : (tsel == 1 ? wvb : wob);
      blk = (p - 4096) & 511;
    }
    const long i = (blk * 256 + tid) * 8;
    const float4 a = *(const float4*)(s + i);
    const float4 b = *(const float4*)(s + i + 4);
    uint4 o;
    o.x = cvt_pk_bf16(a.x, a.y);
    o.y = cvt_pk_bf16(a.z, a.w);
    o.z = cvt_pk_bf16(b.x, b.y);
    o.w = cvt_pk_bf16(b.z, b.w);
    *(uint4*)(d + i) = o;
  } else if (p < 6912) {
    const int r = p - 5632;
    const int z = r >> 8, rr = r & 255;
    const int bx = rr & 15, by = rr >> 4;  // x fastest (original grid order)
    const float* src = z == 0 ? Wq : M + (long)(z - 1) * 1024 * 1024;
    short* dst = z == 0 ? wqt : Mt + (long)(z - 1) * 1024 * 1024;
    const int d0 = bx * 64, e0 = by * 64;
#pragma unroll
    for (int k = 0; k < 16; ++k) {
      int idx = k * 256 + tid; int rr2 = idx >> 6, c = idx & 63;
      t[rr2][c] = f2bf(src[(long)(d0 + rr2) * 1024 + e0 + c]);
    }
    __syncthreads();
#pragma unroll
    for (int k = 0; k < 16; ++k) {
      int idx = k * 256 + tid; int rr2 = idx >> 6, c = idx & 63;
      dst[(long)(e0 + rr2) * 1024 + d0 + c] = t[c][rr2];
    }
  } else {
    const int r = p - 6912;
    const int qt = r & 31, tt = r >> 5;
    if (tid == 0) fshare = 0;
    __syncthreads();
    const float* base = mask + (long)qt * 64 * 2048 + tt * 64;
    const int rr2 = tid >> 2, c = (tid & 3) * 16;
    bool nz = false;
#pragma unroll
    for (int k = 0; k < 4; ++k) {
      float4 v = *(const float4*)(base + (long)rr2 * 2048 + c + k * 4);
      nz = nz | (v.x != 0.f) | (v.y != 0.f) | (v.z != 0.f) | (v.w != 0.f);
    }
    if (nz) fshare = 1;
    __syncthreads();
    if (tid == 0) flags[qt * 32 + tt] = fshare;
  }
}

// ---------------- GEMM core: 128x128 tile = scale * A * B^T (bf16 in, f32 acc) ----------
// BK=32, TRIPLE-buffered (prefetch depth 2, steady vmcnt(8)). Verified
// 2-barrier skeleton (rounds 8-21). If vt != nullptr the epilogue stores
// TRANSPOSED into vt[(bx>>4)*16+by*2+..][dh][s] via an LDS round-trip
// (stride 136 shorts, 2-way-conflict-free) instead of writing C.

template <typename CT>
__device__ __forceinline__ void gemm_core(
    short* pool, const short* __restrict__ Ab, const short* __restrict__ Bb,
    CT* __restrict__ Cb, int N, int K, float scale, short* __restrict__ vt,
    int bx, int by) {
  short* Asb = pool;
  short* Bsb = pool + 12288;
  const int tid = threadIdx.x;
  const int w = tid >> 6, lane = tid & 63;
  const int wr = w >> 1, wc = w & 1;
  const int g = lane >> 4;

  f32x4 acc[4][4];
#pragma unroll
  for (int i = 0; i < 4; ++i)
#pragma unroll
    for (int j = 0; j < 4; ++j) acc[i][j] = {0.f, 0.f, 0.f, 0.f};

  const int srow = lane >> 2;                      // row within 16-row chunk
  const int scol = ((lane & 3) ^ (srow & 3)) * 8;  // pre-swizzled source col (shorts)

  auto STAGE = [&](int bufi, int k0) {
#pragma unroll
    for (int c = 0; c < 2; ++c) {
      const int chunk = w * 2 + c;
      const long gr = (long)(chunk * 16 + srow);
      gload_lds16(Ab + gr * K + k0 + scol, Asb + bufi * 4096 + chunk * 512);
      gload_lds16(Bb + gr * K + k0 + scol, Bsb + bufi * 4096 + chunk * 512);
    }
  };

  auto COMPUTE = [&](int bufi) {
    bf16x8 af[4], bfr[4];
#pragma unroll
    for (int mf = 0; mf < 4; ++mf) {
      const int r = wr * 64 + mf * 16 + (lane & 15);
      const int cb = g ^ (r & 3);
      af[mf] = *(const bf16x8*)&Asb[bufi * 4096 + r * 32 + cb * 8];
    }
#pragma unroll
    for (int nf = 0; nf < 4; ++nf) {
      const int r = wc * 64 + nf * 16 + (lane & 15);
      const int cb = g ^ (r & 3);
      bfr[nf] = *(const bf16x8*)&Bsb[bufi * 4096 + r * 32 + cb * 8];
    }
#pragma unroll
    for (int mf = 0; mf < 4; ++mf)
#pragma unroll
      for (int nf = 0; nf < 4; ++nf)
        acc[mf][nf] =
            __builtin_amdgcn_mfma_f32_16x16x32_bf16(af[mf], bfr[nf], acc[mf][nf], 0, 0, 0);
  };

  const int NK = K >> 5;
  STAGE(0, 0);
  if (NK > 1) STAGE(1, 32);
  for (int it = 0; it < NK; ++it) {
    const int cur = it % 3;
    if (it + 2 < NK) {
      STAGE((it + 2) % 3, (it + 2) * 32);
      asm volatile("s_waitcnt vmcnt(8)" ::: "memory");  // cur-buffer loads done
    } else if (it + 1 < NK) {
      asm volatile("s_waitcnt vmcnt(4)" ::: "memory");
    } else {
      asm volatile("s_waitcnt vmcnt(0)" ::: "memory");
    }
    __builtin_amdgcn_s_barrier();
    __builtin_amdgcn_sched_barrier(0);
    COMPUTE(cur);
    __builtin_amdgcn_sched_barrier(0);
    __builtin_amdgcn_s_barrier();
  }

  const int r0 = g * 4, cc = lane & 15;
  if (vt != nullptr) {
    // ---- fused V^T epilogue: acc -> LDS[dh][s] (stride 136) -> coalesced Vt
    __syncthreads();  // all waves done with As/Bs region
#pragma unroll
    for (int mf = 0; mf < 4; ++mf)
#pragma unroll
      for (int i = 0; i < 4; ++i) {
        const int srow_l = wr * 64 + mf * 16 + r0 + i;  // s within tile
#pragma unroll
        for (int nf = 0; nf < 4; ++nf) {
          const int dh_l = wc * 64 + nf * 16 + cc;      // dh within tile
          pool[dh_l * 136 + srow_l] = f2bf(acc[mf][nf][i]);
        }
      }
    __syncthreads();
    const long bb = bx >> 4;             // batch
    const int s0b = (bx & 15) * 128;     // s within batch
    const int hbase = by * 2;
#pragma unroll
    for (int pass = 0; pass < 4; ++pass) {
      const int dhrow = pass * 32 + (tid >> 3);  // 0..127
      const long vrow = (bb * 16 + hbase + (dhrow >> 6)) * 64 + (dhrow & 63);
      const int cseg = (tid & 7) * 16;
      bf16x8 v0 = *(const bf16x8*)&pool[dhrow * 136 + cseg];
      bf16x8 v1 = *(const bf16x8*)&pool[dhrow * 136 + cseg + 8];
      *(bf16x8*)(vt + vrow * 2048 + s0b + cseg) = v0;
      *(bf16x8*)(vt + vrow * 2048 + s0b + cseg + 8) = v1;
    }
    return;
  }

#pragma unroll
  for (int mf = 0; mf < 4; ++mf)
#pragma unroll
    for (int i = 0; i < 4; ++i) {
      const long row = (long)bx * 128 + wr * 64 + mf * 16 + r0 + i;
#pragma unroll
      for (int nf = 0; nf < 4; ++nf) {
        const long col = (long)by * 128 + wc * 64 + nf * 16 + cc;
        float v = acc[mf][nf][i] * scale;
        if constexpr (__is_same(CT, short))
          Cb[row * (long)N + col] = f2bf(v);
        else
          Cb[row * (long)N + col] = v;
      }
    }
}

// generic batched wrapper (QM, out-proj)
template <typename CT>
__global__ __launch_bounds__(256) void gemm_bt(
    const short* __restrict__ A, const short* __restrict__ B, CT* __restrict__ C,
    int N, int K, long sA, long sB, long sC, float scale) {
  __shared__ __align__(16) short pool[24576];  // 48KB
  const int bx = blockIdx.x, by = blockIdx.y, bz = blockIdx.z;
  gemm_core<CT>(pool, A + (long)bz * sA + (long)bx * 128 * K,
                B + (long)bz * sB + (long)by * 128 * K, C + (long)bz * sC,
                N, K, scale, nullptr, bx, by);
}

// fused KV-projection + Gt, ZERO dead blocks: 1D grid of 1280 blocks.
// p in [0,1024): KV  (z = p>>9, y = (p&511)>>6, x = p&63; z==1 -> Vt epilogue)
// p in [1024,1280): Gt (zz = (p-1024)>>6, y = ((p-1024)&63)>>3, x = (p-1024)&7)
__global__ __launch_bounds__(256) void kvgt_gemm(
    const short* __restrict__ xb, const short* __restrict__ wkv,
    short* __restrict__ Kb, short* __restrict__ Vtb,
    const short* __restrict__ Mtb, const short* __restrict__ wqt,
    short* __restrict__ Gtb) {
  __shared__ __align__(16) short pool[24576];  // 48KB
  constexpr long NW = 1024l * 1024, NX = 4l * 2048 * 1024;
  const int p = blockIdx.x;
  if (p < 1024) {
    const int z = p >> 9, rem = p & 511;
    const int by = rem >> 6, bx = rem & 63;  // original (64,8) order, x fastest
    gemm_core<short>(pool, xb + (long)bx * 128 * 1024,
                     wkv + (long)z * NW + (long)by * 128 * 1024,
                     Kb + (long)z * NX, 1024, 1024, 1.0f,
                     z == 1 ? Vtb : nullptr, bx, by);
  } else {
    const int r = p - 1024;
    const int zz = r >> 6, rr = r & 63;
    const int by = rr >> 3, bx = rr & 7;     // original (8,8) order, x fastest
    gemm_core<short>(pool, Mtb + (long)zz * NW + (long)bx * 128 * 1024,
                     wqt + (long)by * 128 * 1024, Gtb + (long)zz * NW,
                     1024, 1024, 1.0f, nullptr, bx, by);
  }
}

// ---------------- flash attention ----------------
// Verified round-17/20 kernel with XCD-aware 1D grid decode (T1): all 8
// q-blocks of one (b,h) group land on the same XCD (xcd = group&7), so a
// group's K/V slice is fetched into one L2 once instead of 8 copies across
// 8 XCDs. Pure bijective block-index permutation (decode pattern validated
// for correctness in round 12); compute body byte-identical to round 20.
// 512 threads = 8 waves; block covers 256 q-rows, each wave owns 32 q-rows
// as TWO sequential 16-q passes per staged K/V tile.

__global__ __launch_bounds__(512) void flash_attn(
    const short* __restrict__ QM, const short* __restrict__ Kb,
    const short* __restrict__ Vt, const float* __restrict__ mask,
    const int* __restrict__ mflags, short* __restrict__ AO) {
  constexpr int S = 2048, D = 1024, NT = S / 64;
  constexpr float LOG2E = 1.44269504088896f;
  constexpr float CLIP = 50.0f * LOG2E;
  __shared__ __align__(16) short Ks[2][64 * 64];
  __shared__ __align__(16) short Vs[2][64 * 64];
  __shared__ __align__(16) short Ps[8][16 * 64];
  const int tid = threadIdx.x;
  const int w = tid >> 6, lane = tid & 63;
  const int q = lane & 15, g = lane >> 4;
  // XCD-aware decode: p = (grp&7) + 8*((grp>>3)*8 + qb), grp = b*16+h
  const int p = blockIdx.x;            // 0..511
  const int kx = p & 7, j = p >> 3;
  const int qb = j & 7, ghi = j >> 3;
  const int grp = ghi * 8 + kx;        // 0..63
  const int h = grp & 15;
  const long b = grp >> 4;
  const int q0 = qb * 256;

  const short* QMb = QM + (b * S) * D + h * 64;
  const short* Kbp = Kb + (b * S) * D + h * 64;
  const short* Vtp = Vt + ((b * 16 + h) * 64) * S;
  const int qw = q0 + w * 32;  // this wave's 32 q-rows

  bf16x8 qf0[2], qf1[2];
#pragma unroll
  for (int ks = 0; ks < 2; ++ks) {
    qf0[ks] = *(const bf16x8*)(QMb + (long)(qw + q) * D + ks * 32 + g * 8);
    qf1[ks] = *(const bf16x8*)(QMb + (long)(qw + 16 + q) * D + ks * 32 + g * 8);
  }

  bf16x8 onesf;
#pragma unroll
  for (int jj = 0; jj < 8; ++jj) onesf[jj] = (__bf16)1.0f;

  f32x4 accA[4], accB[4];
#pragma unroll
  for (int f = 0; f < 4; ++f) {
    accA[f] = {0.f, 0.f, 0.f, 0.f};
    accB[f] = {0.f, 0.f, 0.f, 0.f};
  }
  f32x4 acc_lA = {0.f, 0.f, 0.f, 0.f};
  f32x4 acc_lB = {0.f, 0.f, 0.f, 0.f};

  const int srow8 = lane >> 3;
  const int scol8 = ((lane & 7) ^ (srow8 & 7)) * 8;
  short* Pw = &Ps[w][0];
  const int psw = (q & 7) << 3;

  auto STAGE = [&](int bufi, int t0) {
    const int row = w * 8 + srow8;
    gload_lds16(Kbp + (long)(t0 + row) * D + scol8, &Ks[bufi][w * 512]);
    gload_lds16(Vtp + (long)row * S + t0 + scol8, &Vs[bufi][w * 512]);
  };

  auto COMPUTE_U = [&](int bufi, int t0, int qrow, const bf16x8 (&qf)[2],
                       f32x4 (&acc)[4], f32x4& acc_l) {
    f32x4 sacc[4];
#pragma unroll
    for (int nf = 0; nf < 4; ++nf) sacc[nf] = {0.f, 0.f, 0.f, 0.f};
    __builtin_amdgcn_s_setprio(1);
#pragma unroll
    for (int ks = 0; ks < 2; ++ks) {
#pragma unroll
      for (int nf = 0; nf < 4; ++nf) {
        const int r = nf * 16 + q;
        const int blk = (ks * 4 + g) ^ (r & 7);
        bf16x8 kf = *(const bf16x8*)&Ks[bufi][r * 64 + blk * 8];
        sacc[nf] = __builtin_amdgcn_mfma_f32_16x16x32_bf16(kf, qf[ks], sacc[nf], 0, 0, 0);
      }
    }
    __builtin_amdgcn_s_setprio(0);

    float pv[4][4];
    const int* flagrowU = mflags + (qrow >> 6) * 32;
    if (__builtin_expect(flagrowU[t0 >> 6], 0)) {
      const float* mrow = mask + (long)(qrow + q) * S + t0;
#pragma unroll
      for (int nf = 0; nf < 4; ++nf) {
        float4 mv = *(const float4*)(mrow + nf * 16 + 4 * g);
        const float* mp = &mv.x;
#pragma unroll
        for (int i = 0; i < 4; ++i)
          pv[nf][i] = exp2_fast(
              __builtin_amdgcn_fmed3f(sacc[nf][i], -CLIP, CLIP) + LOG2E * mp[i]);
      }
    } else {
#pragma unroll
      for (int nf = 0; nf < 4; ++nf)
#pragma unroll
        for (int i = 0; i < 4; ++i)
          pv[nf][i] = exp2_fast(__builtin_amdgcn_fmed3f(sacc[nf][i], -CLIP, CLIP));
    }
#pragma unroll
    for (int nf = 0; nf < 4; ++nf) {
      uint2 u;
      u.x = cvt_pk_bf16(pv[nf][0], pv[nf][1]);
      u.y = cvt_pk_bf16(pv[nf][2], pv[nf][3]);
      *(uint2*)&Pw[q * 64 + ((nf * 16 + 4 * g) ^ psw)] = u;
    }

    mem_fence_compiler();  // P stores (uint2) precede P loads (bf16x8)

    __builtin_amdgcn_s_setprio(1);
#pragma unroll
    for (int ts = 0; ts < 2; ++ts) {
      bf16x8 pfr = *(const bf16x8*)&Pw[q * 64 + ((ts * 32 + 8 * g) ^ psw)];
#pragma unroll
      for (int f = 0; f < 4; ++f) {
        const int vr = f * 16 + q;
        const int vblk = (ts * 4 + g) ^ (vr & 7);
        bf16x8 vf = *(const bf16x8*)&Vs[bufi][vr * 64 + vblk * 8];
        acc[f] = __builtin_amdgcn_mfma_f32_16x16x32_bf16(vf, pfr, acc[f], 0, 0, 0);
      }
      acc_l = __builtin_amdgcn_mfma_f32_16x16x32_bf16(onesf, pfr, acc_l, 0, 0, 0);
    }
    __builtin_amdgcn_s_setprio(0);
    mem_fence_compiler();  // P loads precede the next pass's P stores
  };

  STAGE(0, 0);
  for (int it = 0; it < NT; ++it) {
    const int cur = it & 1;
    if (it + 1 < NT) {
      STAGE(cur ^ 1, (it + 1) * 64);
      asm volatile("s_waitcnt vmcnt(2)" ::: "memory");  // cur-buffer loads done
    } else {
      asm volatile("s_waitcnt vmcnt(0)" ::: "memory");
    }
    __builtin_amdgcn_s_barrier();
    __builtin_amdgcn_sched_barrier(0);
    COMPUTE_U(cur, it * 64, qw, qf0, accA, acc_lA);
    COMPUTE_U(cur, it * 64, qw + 16, qf1, accB, acc_lB);
    __builtin_amdgcn_sched_barrier(0);
    __builtin_amdgcn_s_barrier();
  }

  // epilogue per pass: normalize, transpose O^T -> O via wave-private LDS
  const int qr = lane >> 2, c0 = (lane & 3) * 16;
  short* AOp = AO + (b * S) * D + h * 64;
#pragma unroll
  for (int u = 0; u < 2; ++u) {
    const f32x4* acc = (u == 0) ? accA : accB;
    const float inv = 1.0f / ((u == 0) ? acc_lA[0] : acc_lB[0]);
#pragma unroll
    for (int f = 0; f < 4; ++f) {
      uint2 uu;
      uu.x = cvt_pk_bf16(acc[f][0] * inv, acc[f][1] * inv);
      uu.y = cvt_pk_bf16(acc[f][2] * inv, acc[f][3] * inv);
      *(uint2*)&Pw[q * 64 + ((f * 16 + 4 * g) ^ psw)] = uu;
    }
    mem_fence_compiler();  // O stores (uint2) precede transpose loads (bf16x8)
#pragma unroll
    for (int r2 = 0; r2 < 2; ++r2) {
      const int cc2 = c0 + r2 * 8;
      bf16x8 ov = *(const bf16x8*)&Pw[qr * 64 + (cc2 ^ ((qr & 7) << 3))];
      *(bf16x8*)(AOp + (long)(qw + u * 16 + qr) * D + cc2) = ov;
    }
    mem_fence_compiler();  // transpose loads precede next pass's O stores
  }
}

// ---------------- launch ----------------

extern "C" void kernel_launch(void* const* d_in, const int* in_sizes, int n_in,
                              void* d_out, int out_size, void* d_ws, size_t ws_size,
                              hipStream_t stream) {
  const float* x = (const float*)d_in[0];
  const float* M = (const float*)d_in[1];
  const float* mask = (const float*)d_in[2];
  const float* Wq = (const float*)d_in[3];
  const float* Wk = (const float*)d_in[4];
  const float* Wv = (const float*)d_in[5];
  const float* Wo = (const float*)d_in[6];
  float* out = (float*)d_out;

  constexpr long S = 2048, D = 1024;
  constexpr long NX = 4 * S * D;  // 8388608
  constexpr long NW = D * D;      // 1048576
  constexpr float C1 = 0.125f * 1.44269504088896f;  // 1/sqrt(64) * log2(e)

  short* p = (short*)d_ws;
  short* xb = p;   p += NX;
  short* wkb = p;  p += NW;  // wk, wv contiguous (stride NW) for batched K,V proj
  short* wvb = p;  p += NW;
  short* wob = p;  p += NW;
  short* wqt = p;  p += NW;       // Wq^T  [c][d]
  short* Mtb = p;  p += 4 * NW;   // M^T   [b][e][d]
  short* Gtb = p;  p += 4 * NW;   // G^T = M^T Wq  [b][e][c]
  short* Kb = p;   p += NX;       // K (row-major)
  short* QMb = p;  p += NX;
  short* Vtb = p;  p += NX;       // V^T [b*16+h][dh][s] (written by fused epilogue)
  int* flags = (int*)p;  p += 2048;  // 32x32 tile flags (4KB)
  short* AOb = Mtb;  // Mt+Gt region (8*NW == NX shorts) dead after QM -> reuse for AO

  // ALL preprocessing (x/Wk/Wv/Wo cvt + Wq^T/M^T transpose + mask flags) in
  // ONE 7936-block launch, zero dead blocks
  preproc_all<<<7936, 256, 0, stream>>>(x, xb, Wk, wkb, Wv, wvb, Wo, wob,
                                        Wq, wqt, M, Mtb, mask, flags);

  // K,V projections (V stores transposed to Vtb) + independent G^T GEMM in
  // ONE 1280-block launch, zero dead blocks
  kvgt_gemm<<<1280, 256, 0, stream>>>(xb, wkb, Kb, Vtb, Mtb, wqt, Gtb);
  // QM[b][s][e] = C1 * sum_c x[b][s][c] * Gt[b][e][c]  (fused Q-proj + bilinear,
  // pre-scaled into the log2-softmax domain for flash)
  gemm_bt<short><<<dim3(16, 8, 4), 256, 0, stream>>>(xb, Gtb, QMb, 1024, 1024,
                                                     S * D, NW, S * D, C1);
  flash_attn<<<512, 512, 0, stream>>>(QMb, Kb, Vtb, mask, flags, AOb);
  // out = AO @ Wo^T (f32 store)
  gemm_bt<float><<<dim3(64, 8, 1), 256, 0, stream>>>(AOb, wob, out, 1024, 1024,
                                                     0, 0, 0, 1.0f);
}